// Round 1
// baseline (91.342 us; speedup 1.0000x reference)
//
#include <hip/hip_runtime.h>
#include <math.h>

// Diffusion1D implicit step = tridiagonal solve with constant coefficients.
// r = D*dt/dx^2 = 0.1  ->  A^-1 decays as lambda^|i-j|, lambda ~= 0.0839.
// lambda^9 ~ 2e-10 < fp32 ulp, so each x_i depends only on C[i-8 .. i+8].
// Interior: per-thread 16-output chunk, two register IIR scans (F fwd, B bwd),
//   x_i = G * (F_i + B_i - C_i),  G = 1/sqrt((1+2r)^2 - 4r^2).
// All global traffic is unit-stride float4 via an LDS round-trip (per-thread
// contiguous global access is 64B-lane-strided -> TA-bound at 620 GB/s, R1).
// R3: W 16->8 (-33% FMA, 12->8 ds_read_b128).
// R4 (this round):
//   - Phase A staging via __builtin_amdgcn_global_load_lds width=16: LDS dest
//     stays LINEAR (wave-uniform base + lane*16); the XOR bank swizzle moves
//     to the per-lane GLOBAL source address (swz is an involution closed in
//     64-granule groups, so each wave still reads exactly its own 1KiB span
//     -> coalescing preserved, B/C/D layout unchanged). Kills 5 ds_write_b128
//     + the VGPR round-trip per thread.
//   - Separate 16KB output LDS buffer: removes the middle __syncthreads
//     (3 -> 2 barriers). 33KB LDS still 4 blocks/CU (wave-limited anyway).
// Boundaries (rows 0..39 and nx-40..nx-1): exact Thomas over a 65-row window
// in one extra block (seed/image errors decay by lambda^25 ~ 1e-27).

constexpr int T    = 16;          // outputs per thread
constexpr int W    = 8;           // one-sided stencil half-width
constexpr int BLK  = 256;
constexpr int TILE = BLK * T;     // 4096 elements per interior block
constexpr int BW   = 40;          // boundary width handled by boundary block
constexpr int NWIN = T + 2 * W;   // 32-float window per thread
constexpr int NG   = (TILE + 2 * W) / 4;   // 1028 staged granules (float4)
constexpr int NGO  = TILE / 4;             // 1024 output granules

// XOR bank swizzle on 16B granules: keeps every LDS phase <=2-way aliased.
// Involution (bits 0-2 ^= bits 3-5), closed within 64-granule (1KiB) groups.
__device__ __forceinline__ int swz(int g) { return g ^ ((g >> 3) & 7); }

// Async global->LDS, 16B per lane. LDS dest must be wave-uniform base;
// HW writes dest + lane*16. Per-lane global address carries the swizzle.
__device__ __forceinline__ void gload_lds16(const float4* g, float4* l)
{
    __builtin_amdgcn_global_load_lds(
        (const __attribute__((address_space(1))) void*)g,
        (__attribute__((address_space(3))) void*)l,
        16, 0, 0);
}

__global__ __launch_bounds__(BLK)
void diff1d_kernel(const float* __restrict__ C,
                   const float* __restrict__ dtp,
                   const float* __restrict__ cSp,
                   const float* __restrict__ cBp,
                   float* __restrict__ out, int nx)
{
    float dtf = *dtp;
    float rf  = (1e-9f * dtf) / (1e-4f * 1e-4f);   // = 0.1 for dt=1
    double r    = (double)rf;
    double b0   = 1.0 + 2.0 * r;
    double disc = sqrt(b0 * b0 - 4.0 * r * r);
    float lam = (float)((b0 - disc) / (2.0 * r));  // ~0.08392
    float G   = (float)(1.0 / disc);               // ~0.84515

    int nb_int = gridDim.x - 1;                    // interior blocks

    if ((int)blockIdx.x < nb_int) {
        // ---------------- interior path ----------------
        __shared__ float4 s4[NG];                  // staged input, LINEAR dest
        __shared__ float4 so4[NGO];                // results (separate buffer)

        int tid   = threadIdx.x;
        int tile0 = blockIdx.x * TILE;
        bool edge = (blockIdx.x == 0) || ((int)blockIdx.x == nb_int - 1);

        // Phase A: coalesced stage of [tile0-8, tile0+TILE+8) into LDS.
        // LDS granule p holds global granule swz(p)  (== old s4[swz(g)]=G[g]).
        if (!edge) {
            const float4* gsrc = (const float4*)(C + tile0 - W); // 32B aligned
            int lbase = tid & ~63;                 // wave-uniform lane base
            #pragma unroll
            for (int q = 0; q < 4; ++q) {
                int g = q * BLK + tid;
                gload_lds16(gsrc + swz(g), &s4[q * BLK + lbase]);
            }
            if (tid < NG - 4 * BLK) {              // 4 leftover granules
                int g = 4 * BLK + tid;             // swz(g)==g here (bits3-5=0)
                gload_lds16(gsrc + swz(g), &s4[4 * BLK]);
            }
        } else {
            for (int j = tid; j < TILE + 2 * W; j += BLK) {
                int gi = tile0 - W + j;
                gi = gi < 0 ? 0 : (gi > nx - 1 ? nx - 1 : gi);
                ((float*)&s4[swz(j >> 2)])[j & 3] = C[gi];
            }
        }
        __syncthreads();   // drains vmcnt(0): global_load_lds complete

        // Phase B: per-thread 32-float window from LDS (granules 4t..4t+7)
        float v[NWIN];
        #pragma unroll
        for (int j = 0; j < NWIN / 4; ++j) {
            float4 f = s4[swz(4 * tid + j)];
            v[4 * j + 0] = f.x; v[4 * j + 1] = f.y;
            v[4 * j + 2] = f.z; v[4 * j + 3] = f.w;
        }

        // forward IIR: F_i = sum_{k>=0} lam^k C[i-k] (truncated)
        float F = 0.f;
        float Freg[T];
        #pragma unroll
        for (int k = 0; k < W; ++k) F = fmaf(lam, F, v[k]);
        #pragma unroll
        for (int k = 0; k < T; ++k) { F = fmaf(lam, F, v[W + k]); Freg[k] = F; }

        // backward IIR + combine (overwrite Freg with x to save VGPRs)
        float B = 0.f;
        #pragma unroll
        for (int k = NWIN - 1; k >= W + T; --k) B = fmaf(lam, B, v[k]);
        #pragma unroll
        for (int k = T - 1; k >= 0; --k) {
            B = fmaf(lam, B, v[W + k]);
            Freg[k] = G * (Freg[k] + B - v[W + k]);
        }

        // Phase C: results into the SEPARATE buffer (no barrier needed first)
        #pragma unroll
        for (int q = 0; q < 4; ++q) {
            float4 f;
            f.x = Freg[4 * q + 0]; f.y = Freg[4 * q + 1];
            f.z = Freg[4 * q + 2]; f.w = Freg[4 * q + 3];
            so4[swz(4 * tid + q)] = f;
        }
        __syncthreads();

        // Phase D: coalesced store
        if (!edge) {
            float4* gdst = (float4*)(out + tile0);
            #pragma unroll
            for (int q = 0; q < 4; ++q) {
                int g = q * BLK + tid;
                gdst[g] = so4[swz(g)];
            }
        } else {
            for (int j = tid; j < TILE; j += BLK) {
                int i = tile0 + j;
                if (i >= BW && i <= nx - 1 - BW)
                    out[i] = ((const float*)&so4[swz(j >> 2)])[j & 3];
            }
        }
    } else {
        // ---------------- boundary block (exact Thomas, tiny windows) ------
        __shared__ float cp_s[72], dp_s[72], dpr_s[72];
        float csurf = *cSp, cbulk = *cBp;
        float b0f = 1.0f + 2.0f * rf;

        if (threadIdx.x == 0) {
            // left boundary: exact forward sweep rows 0..64
            cp_s[0] = 0.f;       // row 0: b=1, c=0
            dp_s[0] = csurf;
            for (int j = 1; j <= 64; ++j) {
                float denom = b0f + rf * cp_s[j - 1];     // b - a*cp, a=-r
                cp_s[j] = -rf / denom;
                dp_s[j] = (C[j] + rf * dp_s[j - 1]) / denom;
            }
            // backward; seed error decays by lam^25 before reaching j<40
            float xx = dp_s[64];
            for (int j = 63; j >= 0; --j) {
                xx = dp_s[j] - cp_s[j] * xx;
                if (j < BW) out[j] = xx;
            }
        } else if (threadIdx.x == 64) {
            // right boundary: forward seeded 25 rows early (converged cp)
            float denomc = rf / lam;      // converged denominator
            int s = nx - 65;
            float dpp = 0.f;              // seed; error decays by lam^26
            for (int j = 0; j < 64; ++j) {            // rows s .. nx-2
                dpp = (C[s + j] + rf * dpp) / denomc;
                dpr_s[j] = dpp;
            }
            out[nx - 1] = cbulk;          // row nx-1: x = C_bulk exactly
            float xx = cbulk;
            for (int j = 63; j >= 1; --j) {           // rows nx-2 down
                xx = dpr_s[j] + lam * xx;             // x_j = dp_j - cp* x_{j+1}
                int jj = s + j;
                if (jj >= nx - BW) out[jj] = xx;
            }
        }
    }
}

extern "C" void kernel_launch(void* const* d_in, const int* in_sizes, int n_in,
                              void* d_out, int out_size, void* d_ws, size_t ws_size,
                              hipStream_t stream)
{
    const float* C   = (const float*)d_in[0];
    const float* dtp = (const float*)d_in[1];
    const float* cS  = (const float*)d_in[2];
    const float* cB  = (const float*)d_in[3];
    float* out = (float*)d_out;
    int nx = in_sizes[0];

    int nb = nx / TILE;   // NX = 2^23 is divisible by TILE=4096
    diff1d_kernel<<<nb + 1, BLK, 0, stream>>>(C, dtp, cS, cB, out, nx);
}